// Round 6
// baseline (49469.812 us; speedup 1.0000x reference)
//
#include <hip/hip_runtime.h>
#include <math.h>

#define VOCAB 8000
#define DIM 512
#define NLAYER 8
#define NHEAD 8
#define BATCH 16
#define TMAX 80
#define PROMPT_LEN 64
#define NNEW 16
#define HEADD 64
#define ATT_SCALE 0.125f
#define NPH 42  // phases per decode step

__device__ __forceinline__ float gelu_f(float x) {
  return 0.5f * x * (1.0f + tanhf(0.7978845608028654f * (x + 0.044715f * x * x * x)));
}

// ================= grid phase barrier =================
__device__ __forceinline__ void phase_wait(int* gen, int target) {
  if (threadIdx.x == 0) {
    while (__hip_atomic_load(gen, __ATOMIC_ACQUIRE, __HIP_MEMORY_SCOPE_AGENT) < target)
      __builtin_amdgcn_s_sleep(8);
  }
  __syncthreads();
}

__device__ __forceinline__ void phase_done(int* cnt, int* gen, int idx, int nact) {
  __threadfence();
  __syncthreads();
  if (threadIdx.x == 0) {
    int v = __hip_atomic_fetch_add(&cnt[idx], 1, __ATOMIC_ACQ_REL, __HIP_MEMORY_SCOPE_AGENT);
    if (v == nact - 1)
      __hip_atomic_store(gen, idx + 1, __ATOMIC_RELEASE, __HIP_MEMORY_SCOPE_AGENT);
  }
  __syncthreads();
}

// ================= init =================
__global__ void k_init(const int* __restrict__ ids_in, const int* __restrict__ mask_in,
                       int* __restrict__ ids, int* __restrict__ lens, int* __restrict__ fin,
                       float* __restrict__ csum, float* __restrict__ ccnt, int* __restrict__ cnt,
                       int* __restrict__ gen) {
  int tid = threadIdx.x;
  for (int i = tid; i < BATCH * TMAX; i += blockDim.x) ids[i] = ids_in[i];
  for (int i = tid; i < 1024; i += blockDim.x) cnt[i] = 0;
  if (tid == 0) *gen = 0;
  if (tid < BATCH) {
    int s = 0;
    for (int t = 0; t < TMAX; ++t) s += mask_in[tid * TMAX + t];
    lens[tid] = s;
    fin[tid] = 0;
    csum[tid] = 0.f;
    ccnt[tid] = 0.f;
  }
}

// ================= prefill =================
__global__ void k_embed_prefill(const int* __restrict__ ids, const float* __restrict__ wte,
                                const float* __restrict__ wpe, float* __restrict__ x) {
  int bt = blockIdx.x;
  int b = bt / PROMPT_LEN, t = bt % PROMPT_LEN;
  int tok = ids[b * TMAX + t];
  for (int d = threadIdx.x; d < DIM; d += blockDim.x)
    x[(size_t)bt * DIM + d] = wte[(size_t)tok * DIM + d] + wpe[(size_t)t * DIM + d];
}

__global__ void k_layernorm(const float* __restrict__ x, const float* __restrict__ w,
                            const float* __restrict__ b, float* __restrict__ out) {
  int row = blockIdx.x;
  int tid = threadIdx.x;
  const float* xr = x + (size_t)row * DIM;
  __shared__ float red[256];
  float v0 = xr[tid], v1 = xr[tid + 256];
  red[tid] = v0 + v1;
  __syncthreads();
  for (int s = 128; s > 0; s >>= 1) {
    if (tid < s) red[tid] += red[tid + s];
    __syncthreads();
  }
  float mean = red[0] * (1.0f / DIM);
  __syncthreads();
  float d0 = v0 - mean, d1 = v1 - mean;
  red[tid] = d0 * d0 + d1 * d1;
  __syncthreads();
  for (int s = 128; s > 0; s >>= 1) {
    if (tid < s) red[tid] += red[tid + s];
    __syncthreads();
  }
  float rstd = 1.0f / sqrtf(red[0] * (1.0f / DIM) + 1e-5f);
  out[(size_t)row * DIM + tid] = d0 * rstd * w[tid] + b[tid];
  out[(size_t)row * DIM + tid + 256] = d1 * rstd * w[tid + 256] + b[tid + 256];
}

// MODE: 1 = gelu(+bias), 2 = +bias +res, 3 = qkv epilogue (+bias, write q + KV caches)
template <int MODE>
__global__ __launch_bounds__(256) void gemm_kernel(const float* __restrict__ A,
                                                   const float* __restrict__ W,
                                                   const float* __restrict__ bias,
                                                   const float* __restrict__ res,
                                                   float* __restrict__ C, int M, int N, int K,
                                                   float* __restrict__ kcT,
                                                   float* __restrict__ vc) {
  const int BM = 64, BN = 64, BK = 16;
  __shared__ float As[BK][BM + 4];
  __shared__ float Ws[BK][BN];
  int tid = threadIdx.x;
  int bm = blockIdx.y * BM, bn = blockIdx.x * BN;
  int tr = tid / 16, tc = tid % 16;
  float acc[4][4];
#pragma unroll
  for (int i = 0; i < 4; i++)
#pragma unroll
    for (int j = 0; j < 4; j++) acc[i][j] = 0.f;

  for (int k0 = 0; k0 < K; k0 += BK) {
    for (int i = tid; i < BM * BK; i += 256) {
      int m = i / BK, kk = i % BK;
      As[kk][m] = A[(size_t)(bm + m) * K + k0 + kk];
    }
    for (int i = tid; i < BK * BN; i += 256) {
      int kk = i / BN, n = i % BN;
      Ws[kk][n] = W[(size_t)(k0 + kk) * N + bn + n];
    }
    __syncthreads();
#pragma unroll
    for (int kk = 0; kk < BK; ++kk) {
      float a[4], w[4];
#pragma unroll
      for (int i = 0; i < 4; i++) a[i] = As[kk][tr * 4 + i];
#pragma unroll
      for (int j = 0; j < 4; j++) w[j] = Ws[kk][tc * 4 + j];
#pragma unroll
      for (int i = 0; i < 4; i++)
#pragma unroll
        for (int j = 0; j < 4; j++) acc[i][j] += a[i] * w[j];
    }
    __syncthreads();
  }
#pragma unroll
  for (int i = 0; i < 4; i++) {
    int m = bm + tr * 4 + i;
#pragma unroll
    for (int j = 0; j < 4; j++) {
      int n = bn + tc * 4 + j;
      float v = acc[i][j] + (bias ? bias[n] : 0.f);
      if (MODE == 1) v = gelu_f(v);
      if (MODE == 2) v += res[(size_t)m * N + n];
      if (MODE == 3) {
        int b = m >> 6, t = m & 63;
        if (n < DIM) {
          C[(size_t)m * N + n] = v;
        } else if (n < 2 * DIM) {
          int dd = n - DIM;
          kcT[((size_t)(b * NHEAD + (dd >> 6)) * HEADD + (dd & 63)) * TMAX + t] = v;
        } else {
          int dd = n - 2 * DIM;
          vc[((size_t)(b * NHEAD + (dd >> 6)) * TMAX + t) * HEADD + (dd & 63)] = v;
        }
      } else {
        C[(size_t)m * N + n] = v;
      }
    }
  }
}

__global__ void k_attn_prefill(const float* __restrict__ qkv, const float* __restrict__ kcT,
                               const float* __restrict__ vc, float* __restrict__ o) {
  int blk = blockIdx.x;
  int q = blk % PROMPT_LEN;
  int bh = blk / PROMPT_LEN;
  int h = bh % NHEAD, b = bh / NHEAD;
  int tid = threadIdx.x;  // 64
  __shared__ float qs[HEADD];
  __shared__ float ps[PROMPT_LEN];
  qs[tid] = qkv[(size_t)(b * PROMPT_LEN + q) * 3 * DIM + h * HEADD + tid];
  __syncthreads();
  const float* kbT = kcT + (size_t)(b * NHEAD + h) * HEADD * TMAX;
  const float* vb = vc + (size_t)(b * NHEAD + h) * TMAX * HEADD;
  float s = -1e30f;
  if (tid <= q) {
    float a = 0.f;
    for (int d = 0; d < HEADD; ++d) a += qs[d] * kbT[d * TMAX + tid];
    s = a * ATT_SCALE;
  }
  float mx = s;
  for (int off = 32; off > 0; off >>= 1) mx = fmaxf(mx, __shfl_xor(mx, off));
  float e = (tid <= q) ? expf(s - mx) : 0.f;
  float sum = e;
  for (int off = 32; off > 0; off >>= 1) sum += __shfl_xor(sum, off);
  ps[tid] = e / sum;
  __syncthreads();
  float acc = 0.f;
  for (int t = 0; t <= q; ++t) acc += ps[t] * vb[t * HEADD + tid];
  o[(size_t)(b * PROMPT_LEN + q) * DIM + h * HEADD + tid] = acc;
}

// decode initial embedding -> xa row-major [16][512]
__global__ void k_embed0(const int* __restrict__ ids, const int* __restrict__ lens,
                         const float* __restrict__ wte, const float* __restrict__ wpe,
                         float* __restrict__ xa) {
  int b = blockIdx.x;
  int p = lens[b] - 1;
  if (p < 0) p = 0;
  if (p > TMAX - 1) p = TMAX - 1;
  int tok = ids[b * TMAX + p];
  for (int d = threadIdx.x; d < DIM; d += blockDim.x)
    xa[(size_t)b * DIM + d] = wte[(size_t)tok * DIM + d] + wpe[(size_t)p * DIM + d];
}

// ================= persistent decode helpers =================
#define SMROW 520  // padded LDS row length (floats)

// stage x (row-major [16][512]) + P partials (+opt LN, +opt write xout) into sm[16][520]
__device__ __forceinline__ void stage512(float* sm, const float* x, const float* parts, int P,
                                         const float* lnw, const float* lnb, bool doln,
                                         float* xout, float* smean, float* srstd) {
  const int t = threadIdx.x;
  const int b = t >> 5, j = t & 31;
  const float4* xr = (const float4*)(x + (size_t)b * DIM);
  float s = 0.f, ss = 0.f;
#pragma unroll
  for (int i = 0; i < 4; ++i) {
    int c4 = j + 32 * i;
    float4 v = xr[c4];
    for (int p = 0; p < P; ++p) {
      const float4* pr = (const float4*)(parts + (size_t)p * BATCH * DIM + (size_t)b * DIM);
      float4 tt = pr[c4];
      v.x += tt.x;
      v.y += tt.y;
      v.z += tt.z;
      v.w += tt.w;
    }
    if (xout) ((float4*)(xout + (size_t)b * DIM))[c4] = v;
    if (doln) {
      s += v.x + v.y + v.z + v.w;
      ss += v.x * v.x + v.y * v.y + v.z * v.z + v.w * v.w;
    }
    ((float4*)(sm + b * SMROW))[c4] = v;
  }
  if (doln) {
#pragma unroll
    for (int off = 1; off < 32; off <<= 1) {
      s += __shfl_xor(s, off);
      ss += __shfl_xor(ss, off);
    }
    if (j == 0) {
      float m = s * (1.0f / DIM);
      float var = ss * (1.0f / DIM) - m * m;
      smean[b] = m;
      srstd[b] = rsqrtf(var + 1e-5f);
    }
    __syncthreads();
#pragma unroll
    for (int b2 = 0; b2 < BATCH; ++b2) {
      float vv = sm[b2 * SMROW + t];
      sm[b2 * SMROW + t] = (vv - smean[b2]) * srstd[b2] * lnw[t] + lnb[t];
    }
  }
  __syncthreads();
}

// stage a 512-row slice of gelu(fcp0+fcp1) into sm[16][520]
__device__ __forceinline__ void stage_gelu_slice(float* sm, const float* f0, const float* f1,
                                                 int kb) {
  const int t = threadIdx.x;
  const int b = t >> 5, j = t & 31;
  const float4* a = (const float4*)(f0 + (size_t)b * (4 * DIM) + kb * 512);
  const float4* c = (const float4*)(f1 + (size_t)b * (4 * DIM) + kb * 512);
#pragma unroll
  for (int i = 0; i < 4; ++i) {
    int c4 = j + 32 * i;
    float4 v = a[c4], w = c[c4];
    v.x = gelu_f(v.x + w.x);
    v.y = gelu_f(v.y + w.y);
    v.z = gelu_f(v.z + w.z);
    v.w = gelu_f(v.w + w.w);
    ((float4*)(sm + b * SMROW))[c4] = v;
  }
  __syncthreads();
}

// K-loop: wave w covers [w*chunk,(w+1)*chunk) of this block's k-slice
template <int LDW>
__device__ __forceinline__ void gemm_core(const float* sm, int krow0, int nrows,
                                          const float* Wcol, float* acc) {
  const int w = threadIdx.x >> 6;
  const int chunk = nrows >> 3;
  const int k0 = w * chunk;
#pragma unroll
  for (int i = 0; i < 16; ++i) acc[i] = 0.f;
  for (int k = 0; k < chunk; k += 8) {
    float wv[8];
#pragma unroll
    for (int u = 0; u < 8; ++u) wv[u] = Wcol[(size_t)(k0 + k + u) * LDW];
#pragma unroll
    for (int u = 0; u < 8; ++u) {
      const float* ar = sm + (krow0 + k0 + k + u);
#pragma unroll
      for (int b = 0; b < BATCH; ++b) acc[b] = fmaf(ar[(size_t)b * SMROW], wv[u], acc[b]);
    }
  }
}

// cross-wave reduce (reuses sm) + store row-major out[b*ldout + col0 + n]
__device__ __forceinline__ void reduce_store(float* sm, const float* acc, const float* bias,
                                             bool addbias, float* outp, int ldout, int col0) {
  __syncthreads();  // done reading staged A
  const int lane = threadIdx.x & 63, w = threadIdx.x >> 6;
#pragma unroll
  for (int b = 0; b < BATCH; ++b) sm[(w * BATCH + b) * 64 + lane] = acc[b];
  __syncthreads();
  for (int o = threadIdx.x; o < BATCH * 64; o += 512) {
    int b = o >> 6, n = o & 63;
    float v = 0.f;
#pragma unroll
    for (int ww = 0; ww < 8; ++ww) v += sm[(ww * BATCH + b) * 64 + n];
    if (addbias) v += bias[col0 + n];
    outp[(size_t)b * ldout + col0 + n] = v;
  }
}

// ================= persistent decode kernel =================
__global__ __launch_bounds__(512) void k_decode(
    const float* __restrict__ wte, const float* __restrict__ wpe, const float* __restrict__ ln1_w,
    const float* __restrict__ ln1_b, const float* __restrict__ qkv_w,
    const float* __restrict__ qkv_b, const float* __restrict__ ao_w,
    const float* __restrict__ ao_b, const float* __restrict__ ln2_w,
    const float* __restrict__ ln2_b, const float* __restrict__ fc_w,
    const float* __restrict__ fc_b, const float* __restrict__ pr_w,
    const float* __restrict__ pr_b, const float* __restrict__ lnf_w,
    const float* __restrict__ lnf_b, const float* __restrict__ lm_w, int* __restrict__ ids,
    int* __restrict__ lens, int* __restrict__ fin, float* __restrict__ csum,
    float* __restrict__ ccnt, float* __restrict__ xa, float* __restrict__ xb,
    float* __restrict__ qkvp, float* __restrict__ o, float* __restrict__ aop,
    float* __restrict__ fcp, float* __restrict__ prp, float* __restrict__ logp,
    float* __restrict__ kc, float* __restrict__ vc, float* __restrict__ out, int* cnt, int* gen) {
  __shared__ float sm[BATCH * SMROW];
  __shared__ float smean[BATCH], srstd[BATCH];
  __shared__ float sred[8];
  __shared__ int sired[8];
  __shared__ float smx;
  __shared__ int stop, stok, spos;
  const int bx = blockIdx.x;
  const int tid = threadIdx.x;
  if (bx >= 250) return;  // never participates
  float acc[16];
  const size_t kvstride = (size_t)BATCH * NHEAD * TMAX * HEADD;

  for (int s = 0; s < NNEW; ++s) {
    const int base = s * NPH;
    for (int l = 0; l < NLAYER; ++l) {
      int ph = base + l * 5;
      // ---- QKV: 48 blocks (24 col-tiles x 2 kparts) ----
      if (bx < 48) {
        phase_wait(gen, ph);
        int ct = bx % 24, kb = bx / 24;
        stage512(sm, xa, prp, (l == 0) ? 0 : 4, ln1_w + l * DIM, ln1_b + l * DIM, true,
                 (bx == 0) ? xb : nullptr, smean, srstd);
        gemm_core<3 * DIM>(sm, kb * 256, 256,
                           qkv_w + (size_t)l * DIM * 3 * DIM + (size_t)(kb * 256) * 3 * DIM +
                               ct * 64 + (tid & 63),
                           acc);
        reduce_store(sm, acc, qkv_b + (size_t)l * 3 * DIM, kb == 0,
                     qkvp + (size_t)kb * BATCH * 3 * DIM, 3 * DIM, ct * 64);
        phase_done(cnt, gen, ph, 48);
      }
      // ---- attention: 128 blocks (b,h) ----
      ph++;
      if (bx < 128) {
        phase_wait(gen, ph);
        int b = bx >> 3, h = bx & 7;
        int p = lens[b] - 1;
        if (p < 0) p = 0;
        if (p > TMAX - 1) p = TMAX - 1;
        float* kT = kc + (size_t)l * kvstride + (size_t)(b * NHEAD + h) * HEADD * TMAX;
        float* vb = vc + (size_t)l * kvstride + (size_t)(b * NHEAD + h) * TMAX * HEADD;
        const float* qp0 = qkvp + (size_t)b * 3 * DIM + h * HEADD;
        const float* qp1 = qkvp + (size_t)BATCH * 3 * DIM + (size_t)b * 3 * DIM + h * HEADD;
        float qv = 0.f, kself = 0.f, vself = 0.f;
        if (tid < 64) {
          qv = qp0[tid] + qp1[tid];
          kself = qp0[DIM + tid] + qp1[DIM + tid];
          vself = qp0[2 * DIM + tid] + qp1[2 * DIM + tid];
          kT[tid * TMAX + p] = kself;
          vb[p * HEADD + tid] = vself;
          sm[tid] = qv;
        }
        __syncthreads();
        if (tid < 64) {
          float pd = qv * kself;
          for (int off = 32; off > 0; off >>= 1) pd += __shfl_xor(pd, off);
          float selfdot = pd * ATT_SCALE;
          float s0 = -1e30f, s1 = -1e30f;
          int t1 = tid + 64;
          if (tid < p) {
            float a = 0.f;
            for (int dd = 0; dd < HEADD; ++dd) a += sm[dd] * kT[dd * TMAX + tid];
            s0 = a * ATT_SCALE;
          } else if (tid == p) {
            s0 = selfdot;
          }
          if (t1 < p) {
            float a = 0.f;
            for (int dd = 0; dd < HEADD; ++dd) a += sm[dd] * kT[dd * TMAX + t1];
            s1 = a * ATT_SCALE;
          } else if (t1 == p) {
            s1 = selfdot;
          }
          float mx = fmaxf(s0, s1);
          for (int off = 32; off > 0; off >>= 1) mx = fmaxf(mx, __shfl_xor(mx, off));
          float e0 = (tid <= p) ? expf(s0 - mx) : 0.f;
          float e1 = (t1 <= p) ? expf(s1 - mx) : 0.f;
          float sum = e0 + e1;
          for (int off = 32; off > 0; off >>= 1) sum += __shfl_xor(sum, off);
          float inv = 1.f / sum;
          sm[64 + tid] = e0 * inv;
          if (tid < TMAX - 64) sm[64 + t1] = e1 * inv;
        }
        __syncthreads();
        if (tid < 64) {
          float a = 0.f;
          for (int t = 0; t < p; ++t) a += sm[64 + t] * vb[t * HEADD + tid];
          a += sm[64 + p] * vself;
          o[(size_t)b * DIM + h * HEADD + tid] = a;
        }
        phase_done(cnt, gen, ph, 128);
      }
      // ---- AO: 16 blocks (8 x 2) ----
      ph++;
      if (bx < 16) {
        phase_wait(gen, ph);
        int ct = bx % 8, kb = bx / 8;
        stage512(sm, o, nullptr, 0, nullptr, nullptr, false, nullptr, smean, srstd);
        gemm_core<DIM>(sm, kb * 256, 256,
                       ao_w + (size_t)l * DIM * DIM + (size_t)(kb * 256) * DIM + ct * 64 +
                           (tid & 63),
                       acc);
        reduce_store(sm, acc, ao_b + (size_t)l * DIM, kb == 0, aop + (size_t)kb * BATCH * DIM,
                     DIM, ct * 64);
        phase_done(cnt, gen, ph, 16);
      }
      // ---- FC: 64 blocks (32 x 2) ----
      ph++;
      if (bx < 64) {
        phase_wait(gen, ph);
        int ct = bx % 32, kb = bx / 32;
        stage512(sm, xb, aop, 2, ln2_w + l * DIM, ln2_b + l * DIM, true,
                 (bx == 0) ? xa : nullptr, smean, srstd);
        gemm_core<4 * DIM>(sm, kb * 256, 256,
                           fc_w + (size_t)l * DIM * 4 * DIM + (size_t)(kb * 256) * 4 * DIM +
                               ct * 64 + (tid & 63),
                           acc);
        reduce_store(sm, acc, fc_b + (size_t)l * 4 * DIM, kb == 0,
                     fcp + (size_t)kb * BATCH * 4 * DIM, 4 * DIM, ct * 64);
        phase_done(cnt, gen, ph, 64);
      }
      // ---- PR: 32 blocks (8 x 4) ----
      ph++;
      if (bx < 32) {
        phase_wait(gen, ph);
        int ct = bx % 8, kb = bx / 8;
        stage_gelu_slice(sm, fcp, fcp + (size_t)BATCH * 4 * DIM, kb);
        gemm_core<DIM>(sm, 0, 512,
                       pr_w + (size_t)l * 4 * DIM * DIM + (size_t)(kb * 512) * DIM + ct * 64 +
                           (tid & 63),
                       acc);
        reduce_store(sm, acc, pr_b + (size_t)l * DIM, kb == 0, prp + (size_t)kb * BATCH * DIM,
                     DIM, ct * 64);
        phase_done(cnt, gen, ph, 32);
      }
    }
    // ---- LM: 250 blocks (125 col-tiles x 2 kparts) ----
    {
      int ph = base + 40;
      if (bx < 250) {
        phase_wait(gen, ph);
        int ct = bx % 125, kb = bx / 125;
        stage512(sm, xa, prp, 4, lnf_w, lnf_b, true, nullptr, smean, srstd);
        gemm_core<VOCAB>(sm, kb * 256, 256,
                         lm_w + (size_t)(kb * 256) * VOCAB + ct * 64 + (tid & 63), acc);
        reduce_store(sm, acc, nullptr, false, logp + (size_t)kb * BATCH * VOCAB, VOCAB, ct * 64);
        phase_done(cnt, gen, ph, 250);
      }
    }
    // ---- update: 16 blocks (one per batch row) ----
    {
      int ph = base + 41;
      if (bx < 16) {
        phase_wait(gen, ph);
        int b = bx;
        const float* lr0 = logp + (size_t)b * VOCAB;
        const float* lr1 = logp + (size_t)BATCH * VOCAB + (size_t)b * VOCAB;
        float best = -3e38f;
        int besti = VOCAB;
        for (int i = tid; i < VOCAB; i += 512) {
          float v = lr0[i] + lr1[i];
          if (v > best) {
            best = v;
            besti = i;
          }
        }
#pragma unroll
        for (int off = 1; off < 64; off <<= 1) {
          float ov = __shfl_xor(best, off);
          int oi = __shfl_xor(besti, off);
          if (ov > best || (ov == best && oi < besti)) {
            best = ov;
            besti = oi;
          }
        }
        int w = tid >> 6, lane = tid & 63;
        if (lane == 0) {
          sred[w] = best;
          sired[w] = besti;
        }
        __syncthreads();
        if (tid == 0) {
          float bb = sred[0];
          int bi = sired[0];
#pragma unroll
          for (int ww = 1; ww < 8; ++ww) {
            if (sred[ww] > bb || (sred[ww] == bb && sired[ww] < bi)) {
              bb = sred[ww];
              bi = sired[ww];
            }
          }
          smx = bb;
          stop = bi;
        }
        __syncthreads();
        float mx = smx;
        float se = 0.f;
        for (int i = tid; i < VOCAB; i += 512) se += expf(lr0[i] + lr1[i] - mx);
#pragma unroll
        for (int off = 1; off < 64; off <<= 1) se += __shfl_xor(se, off);
        if (lane == 0) sred[w] = se;
        __syncthreads();
        if (tid == 0) {
          float denom = 0.f;
#pragma unroll
          for (int ww = 0; ww < 8; ++ww) denom += sred[ww];
          float top_p = 1.f / denom;
          int top = stop;
          int l = lens[b];
          bool active = (!fin[b]) && (l < TMAX);
          if (active) {
            csum[b] += top_p;
            ccnt[b] += 1.f;
          }
          bool is_end = (top == 3) || (top == 0);
          bool wr = active && !is_end;
          if (wr) {
            ids[b * TMAX + l] = top;
            lens[b] = l + 1;
          }
          if (active && is_end) fin[b] = 1;
          out[b * NNEW + s] = wr ? (float)top : 0.f;
          if (s == NNEW - 1) out[BATCH * NNEW + b] = csum[b] / fmaxf(ccnt[b], 1.f);
          int pn = lens[b] - 1;
          if (pn < 0) pn = 0;
          if (pn > TMAX - 1) pn = TMAX - 1;
          spos = pn;
          stok = ids[b * TMAX + pn];
        }
        __syncthreads();
        int tok = stok, pn = spos;
        xa[(size_t)b * DIM + tid] = wte[(size_t)tok * DIM + tid] + wpe[(size_t)pn * DIM + tid];
        phase_done(cnt, gen, ph, 16);
      }
    }
  }
}

// ================= host launch =================
extern "C" void kernel_launch(void* const* d_in, const int* in_sizes, int n_in, void* d_out,
                              int out_size, void* d_ws, size_t ws_size, hipStream_t stream) {
  const float* wte = (const float*)d_in[0];
  const float* wpe = (const float*)d_in[1];
  const float* ln1_w = (const float*)d_in[2];
  const float* ln1_b = (const float*)d_in[3];
  const float* qkv_w = (const float*)d_in[4];
  const float* qkv_b = (const float*)d_in[5];
  const float* ao_w = (const float*)d_in[6];
  const float* ao_b = (const float*)d_in[7];
  const float* ln2_w = (const float*)d_in[8];
  const float* ln2_b = (const float*)d_in[9];
  const float* fc_w = (const float*)d_in[10];
  const float* fc_b = (const float*)d_in[11];
  const float* pr_w = (const float*)d_in[12];
  const float* pr_b = (const float*)d_in[13];
  const float* lnf_w = (const float*)d_in[14];
  const float* lnf_b = (const float*)d_in[15];
  const float* lm_w = (const float*)d_in[16];
  const int* ids_in = (const int*)d_in[17];
  const int* mask_in = (const int*)d_in[18];
  float* out = (float*)d_out;

  char* p = (char*)d_ws;
  auto carve = [&](size_t nbytes) {
    char* r = p;
    p += (nbytes + 255) & ~(size_t)255;
    return (void*)r;
  };
  int* w_ids = (int*)carve(BATCH * TMAX * 4);
  int* w_lens = (int*)carve(BATCH * 4);
  int* w_fin = (int*)carve(BATCH * 4);
  float* w_csum = (float*)carve(BATCH * 4);
  float* w_ccnt = (float*)carve(BATCH * 4);
  int* w_cnt = (int*)carve(1024 * 4);
  int* w_gen = (int*)carve(256);
  float* w_x = (float*)carve((size_t)BATCH * PROMPT_LEN * DIM * 4);
  float* w_h = (float*)carve((size_t)BATCH * PROMPT_LEN * DIM * 4);
  float* w_qkv = (float*)carve((size_t)BATCH * PROMPT_LEN * 3 * DIM * 4);
  float* w_att = (float*)carve((size_t)BATCH * PROMPT_LEN * DIM * 4);
  float* w_mlp = (float*)carve((size_t)BATCH * PROMPT_LEN * 4 * DIM * 4);
  float* w_kc = (float*)carve((size_t)NLAYER * BATCH * NHEAD * TMAX * HEADD * 4);
  float* w_vc = (float*)carve((size_t)NLAYER * BATCH * NHEAD * TMAX * HEADD * 4);
  float* w_xa = (float*)carve((size_t)BATCH * DIM * 4);
  float* w_xb = (float*)carve((size_t)BATCH * DIM * 4);
  float* w_o = (float*)carve((size_t)BATCH * DIM * 4);
  float* w_qkp = (float*)carve((size_t)2 * BATCH * 3 * DIM * 4);
  float* w_aop = (float*)carve((size_t)2 * BATCH * DIM * 4);
  float* w_fcp = (float*)carve((size_t)2 * BATCH * 4 * DIM * 4);
  float* w_prp = (float*)carve((size_t)4 * BATCH * DIM * 4);
  float* w_logp = (float*)carve((size_t)2 * BATCH * VOCAB * 4);

  const int M = BATCH * PROMPT_LEN;  // 1024
  const size_t kvstride = (size_t)BATCH * NHEAD * TMAX * HEADD;

  k_init<<<1, 256, 0, stream>>>(ids_in, mask_in, w_ids, w_lens, w_fin, w_csum, w_ccnt, w_cnt,
                                w_gen);
  k_embed_prefill<<<M, 256, 0, stream>>>(w_ids, wte, wpe, w_x);

  for (int l = 0; l < NLAYER; ++l) {
    float* kc = w_kc + (size_t)l * kvstride;
    float* vc = w_vc + (size_t)l * kvstride;
    k_layernorm<<<M, 256, 0, stream>>>(w_x, ln1_w + l * DIM, ln1_b + l * DIM, w_h);
    gemm_kernel<3><<<dim3(3 * DIM / 64, M / 64), 256, 0, stream>>>(
        w_h, qkv_w + (size_t)l * DIM * 3 * DIM, qkv_b + (size_t)l * 3 * DIM, nullptr, w_qkv, M,
        3 * DIM, DIM, kc, vc);
    k_attn_prefill<<<BATCH * NHEAD * PROMPT_LEN, 64, 0, stream>>>(w_qkv, kc, vc, w_att);
    gemm_kernel<2><<<dim3(DIM / 64, M / 64), 256, 0, stream>>>(
        w_att, ao_w + (size_t)l * DIM * DIM, ao_b + (size_t)l * DIM, w_x, w_x, M, DIM, DIM,
        nullptr, nullptr);
    k_layernorm<<<M, 256, 0, stream>>>(w_x, ln2_w + l * DIM, ln2_b + l * DIM, w_h);
    gemm_kernel<1><<<dim3(4 * DIM / 64, M / 64), 256, 0, stream>>>(
        w_h, fc_w + (size_t)l * DIM * 4 * DIM, fc_b + (size_t)l * 4 * DIM, nullptr, w_mlp, M,
        4 * DIM, DIM, nullptr, nullptr);
    gemm_kernel<2><<<dim3(DIM / 64, M / 64), 256, 0, stream>>>(
        w_mlp, pr_w + (size_t)l * 4 * DIM * DIM, pr_b + (size_t)l * DIM, w_x, w_x, M, DIM,
        4 * DIM, nullptr, nullptr);
  }

  k_embed0<<<BATCH, 512, 0, stream>>>(w_ids, w_lens, wte, wpe, w_xa);

  k_decode<<<256, 512, 0, stream>>>(wte, wpe, ln1_w, ln1_b, qkv_w, qkv_b, ao_w, ao_b, ln2_w,
                                    ln2_b, fc_w, fc_b, pr_w, pr_b, lnf_w, lnf_b, lm_w, w_ids,
                                    w_lens, w_fin, w_csum, w_ccnt, w_xa, w_xb, w_qkp, w_o, w_aop,
                                    w_fcp, w_prp, w_logp, w_kc, w_vc, out, w_cnt, w_gen);
}